// Round 17
// baseline (86.818 us; speedup 1.0000x reference)
//
#include <hip/hip_runtime.h>
#include <hip/hip_bf16.h>

#define NE     64
#define HDIM   4096
#define NTOK   16384
#define KSPLIT 8
#define KPER   (HDIM / KSPLIT)   // 512
#define KC     32                // k per LDS tile
#define NT     (KPER / KC)       // 16 tiles per block
#define NCHUNK (HDIM / 32)       // 128 global k-chunks
#define TOKB   64                // tokens per block (2 waves x 32) — R17 change
#define PT     66                // LDS token stride (floats): bank=(2k+t)%32, <=2-way

typedef __attribute__((ext_vector_type(8))) short bf16x8;   // 8 bf16 = 4 VGPR
typedef __attribute__((ext_vector_type(4))) float f32x4;    // MFMA acc

union FragU { uint4 u; bf16x8 v; };

// round-to-nearest-even f32 -> bf16 (bits), no NaN handling (inputs finite)
__device__ __forceinline__ unsigned rne_bf16(float f) {
    unsigned v = __float_as_uint(f);
    return (v + 0x7FFFu + ((v >> 16) & 1u)) >> 16;
}

// split 8 fp32 -> hi (truncate) + lo (rne of residual); numerics identical R4-R16
__device__ __forceinline__ void split8f(const float* s, FragU& hi, FragU& lo) {
#pragma unroll
    for (int w = 0; w < 4; ++w) {
        const unsigned u0 = __float_as_uint(s[2 * w]);
        const unsigned u1 = __float_as_uint(s[2 * w + 1]);
        const unsigned h0 = u0 & 0xFFFF0000u, h1 = u1 & 0xFFFF0000u;
        ((unsigned*)&hi.u)[w] = (h0 >> 16) | h1;
        const float l0 = __uint_as_float(u0) - __uint_as_float(h0);
        const float l1 = __uint_as_float(u1) - __uint_as_float(h1);
        ((unsigned*)&lo.u)[w] = rne_bf16(l0) | (rne_bf16(l1) << 16);
    }
}

// ---------------------------------------------------------------------------
// Pack W [64][4096] fp32 into MFMA B-fragment order, split hi/lo bf16.
// elem j of lane l at [(chunk*4+etile)*64+l] = W[etile*16+(l&15)][chunk*32+(l>>4)*8+j]
// ---------------------------------------------------------------------------
__global__ __launch_bounds__(256) void prep_w(
    const float* __restrict__ W, uint4* __restrict__ wfh, uint4* __restrict__ wfl) {
    const int idx = blockIdx.x * 256 + threadIdx.x;   // 32768 = 128*4*64
    const int l  = idx & 63;
    const int ce = idx >> 6;
    const int e  = ce & 3;
    const int c  = ce >> 2;
    const float* src = W + (size_t)(e * 16 + (l & 15)) * HDIM + c * 32 + (l >> 4) * 8;

    unsigned hw[4], lw[4];
#pragma unroll
    for (int w = 0; w < 4; ++w) {
        const float x0 = src[2 * w], x1 = src[2 * w + 1];
        const unsigned u0 = __float_as_uint(x0), u1 = __float_as_uint(x1);
        const unsigned h0 = u0 & 0xFFFF0000u, h1 = u1 & 0xFFFF0000u;
        hw[w] = (h0 >> 16) | h1;
        const float l0 = x0 - __uint_as_float(h0);
        const float l1 = x1 - __uint_as_float(h1);
        lw[w] = rne_bf16(l0) | (rne_bf16(l1) << 16);
    }
    wfh[idx] = make_uint4(hw[0], hw[1], hw[2], hw[3]);
    wfl[idx] = make_uint4(lw[0], lw[1], lw[2], lw[3]);
}

#define MFMA_STEP(AH0, AL0, AH1, AL1, WH, WL)                                          \
    _Pragma("unroll")                                                                   \
    for (int e = 0; e < 4; ++e) {                                                       \
        acc[0][e] = __builtin_amdgcn_mfma_f32_16x16x32_bf16(AH0.v, WH[e].v, acc[0][e], 0, 0, 0); \
        acc[0][e] = __builtin_amdgcn_mfma_f32_16x16x32_bf16(AL0.v, WH[e].v, acc[0][e], 0, 0, 0); \
        acc[0][e] = __builtin_amdgcn_mfma_f32_16x16x32_bf16(AH0.v, WL[e].v, acc[0][e], 0, 0, 0); \
        acc[1][e] = __builtin_amdgcn_mfma_f32_16x16x32_bf16(AH1.v, WH[e].v, acc[1][e], 0, 0, 0); \
        acc[1][e] = __builtin_amdgcn_mfma_f32_16x16x32_bf16(AL1.v, WH[e].v, acc[1][e], 0, 0, 0); \
        acc[1][e] = __builtin_amdgcn_mfma_f32_16x16x32_bf16(AH1.v, WL[e].v, acc[1][e], 0, 0, 0); \
    }

// ---------------------------------------------------------------------------
// GEMM via split-bf16 MFMA — EXACT R11 pipeline with ONE isolated change:
// 2-wave blocks (TOKB=64, 128 threads, LDS 16.9KB) -> 8 independent blocks
// per CU instead of 4 phase-locked ones. Same 16 waves/CU, but 8 separate
// barrier domains: drains desynchronize and overlap other blocks' loads
// (MLP doubles). Bank pattern (2k+t)%32 identical (66 ≡ 130 mod 32).
// ---------------------------------------------------------------------------
__global__ __launch_bounds__(128) void gemm_logits_mfma(
    const float* __restrict__ x, const uint4* __restrict__ wfh,
    const uint4* __restrict__ wfl, float* __restrict__ part0,
    float* __restrict__ wspart) {
    __shared__ float xs[2][KC][PT];   // 16,896 B

    const int tid  = threadIdx.x;
    const int lane = tid & 63;
    const int wv   = tid >> 6;            // wave 0..1
    const int t0   = blockIdx.x * TOKB;
    const int bk   = blockIdx.y;          // 0..7 k-split
    const int r    = lane & 15;           // A token row in frag / B expert row
    const int u    = lane >> 4;           // 0..3 k-quad

    f32x4 acc[2][4];
#pragma unroll
    for (int f = 0; f < 2; ++f)
#pragma unroll
        for (int e = 0; e < 4; ++e) acc[f][e] = (f32x4){0.f, 0.f, 0.f, 0.f};

    // staging: 8 consecutive tids cover one row's 128B k-chunk (coalesced)
    const int srow = tid >> 3;            // 0..15 (+16p)
    const int skq  = tid & 7;
    const float* gsrc = x + (size_t)(t0 + srow) * HDIM + bk * KPER + skq * 4;

    const uint4* whb = wfh + (size_t)(bk * NT) * 256 + lane;
    const uint4* wlb = wfl + (size_t)(bk * NT) * 256 + lane;

    float4 ldE[4], ldO[4];
    FragU WhA[4], WlA[4], WhB[4], WlB[4];

#define LOADT(LD, T)                                                              \
    _Pragma("unroll")                                                             \
    for (int p = 0; p < 4; ++p)                                                   \
        LD[p] = *reinterpret_cast<const float4*>(gsrc + (size_t)(16 * p) * HDIM + (T) * KC);

#define WRITET(B, LD)                                                             \
    _Pragma("unroll")                                                             \
    for (int p = 0; p < 4; ++p) {                                                 \
        const int rr = srow + 16 * p;                                             \
        xs[B][skq * 4 + 0][rr] = LD[p].x;                                         \
        xs[B][skq * 4 + 1][rr] = LD[p].y;                                         \
        xs[B][skq * 4 + 2][rr] = LD[p].z;                                         \
        xs[B][skq * 4 + 3][rr] = LD[p].w;                                         \
    }

    // Prologue: W(0)->A; tiles 0,1,2 in flight; tile 0 written to buf0.
#pragma unroll
    for (int e = 0; e < 4; ++e) { WhA[e].u = whb[e * 64]; WlA[e].u = wlb[e * 64]; }
    LOADT(ldE, 0)
    LOADT(ldO, 1)
    WRITET(0, ldE)
    LOADT(ldE, 2)
    __syncthreads();

    const int crow = wv * 32 + r;

    for (int t2 = 0; t2 < NT; t2 += 2) {
        // ===== even tile t2: buf0, W set A; ldO holds tile t2+1 =====
        {
            const size_t c = (size_t)(t2 + 1) * 256;
#pragma unroll
            for (int e = 0; e < 4; ++e) { WhB[e].u = whb[c + e * 64]; WlB[e].u = wlb[c + e * 64]; }
            float a0[8], a1[8];
            const float* xb = &xs[0][0][0] + (u * 8) * PT + crow;
#pragma unroll
            for (int j = 0; j < 8; ++j) { a0[j] = xb[j * PT]; a1[j] = xb[j * PT + 16]; }
            FragU ah0, al0, ah1, al1;
            split8f(a0, ah0, al0);
            split8f(a1, ah1, al1);
            MFMA_STEP(ah0, al0, ah1, al1, WhA, WlA)
            WRITET(1, ldO)
            if (t2 + 3 < NT) { LOADT(ldO, t2 + 3) }
            __syncthreads();
        }
        // ===== odd tile t2+1: buf1, W set B; ldE holds tile t2+2 =====
        {
            const int tn = t2 + 2;
            if (tn < NT) {
                const size_t c = (size_t)tn * 256;
#pragma unroll
                for (int e = 0; e < 4; ++e) { WhA[e].u = whb[c + e * 64]; WlA[e].u = wlb[c + e * 64]; }
            }
            float a0[8], a1[8];
            const float* xb = &xs[1][0][0] + (u * 8) * PT + crow;
#pragma unroll
            for (int j = 0; j < 8; ++j) { a0[j] = xb[j * PT]; a1[j] = xb[j * PT + 16]; }
            FragU ah0, al0, ah1, al1;
            split8f(a0, ah0, al0);
            split8f(a1, ah1, al1);
            MFMA_STEP(ah0, al0, ah1, al1, WhB, WlB)
            if (tn < NT) {
                WRITET(0, ldE)
                if (t2 + 4 < NT) { LOADT(ldE, t2 + 4) }
                __syncthreads();
            }
        }
    }

    // D layout (m89-verified, identical to passing R4-R16): lane holds
    // D[token = wv*32 + f*16 + u*4 + reg][expert = e*16 + r]
    float* dst = (bk == 0 ? part0 : wspart + (size_t)(bk - 1) * NTOK * NE);
#pragma unroll
    for (int f = 0; f < 2; ++f)
#pragma unroll
        for (int e = 0; e < 4; ++e)
#pragma unroll
            for (int rr = 0; rr < 4; ++rr)
                dst[(size_t)(t0 + wv * 32 + f * 16 + u * 4 + rr) * NE + e * 16 + r] = acc[f][e][rr];
#undef LOADT
#undef WRITET
}

// ---------------------------------------------------------------------------
// Router: WAVE-PER-TOKEN, lane = expert (R11, proven). Coalesced 256B rows;
// softmax via shfl_xor butterflies; top-2 via packed 64-bit key max-reduce
// (tie -> lowest index, matching jax.lax.top_k; scores >= 0).
// Out layout: [scores 16384*64][logits 16384*64][weights 16384*2][indices 16384*2]
// ---------------------------------------------------------------------------
__global__ __launch_bounds__(256) void router_kernel(
    const float* __restrict__ wspart, const float* __restrict__ mask,
    float* __restrict__ out, int ksplit) {
    const int lane = threadIdx.x & 63;
    const int wv   = threadIdx.x >> 6;
    const int t    = blockIdx.x * 4 + wv;

    // logits: partial 0 lives in the out-logits region; add ws partials
    float* lo = out + (size_t)NTOK * NE + (size_t)t * NE;
    float l = lo[lane];
    for (int c = 1; c < ksplit; ++c)
        l += wspart[((size_t)(c - 1) * NTOK + t) * NE + lane];
    lo[lane] = l;

    // softmax over 64 lanes
    float mx = l;
#pragma unroll
    for (int m = 32; m; m >>= 1) mx = fmaxf(mx, __shfl_xor(mx, m, 64));
    const float ev = __expf(l - mx);
    float s = ev;
#pragma unroll
    for (int m = 32; m; m >>= 1) s += __shfl_xor(s, m, 64);
    const float sc = mask[(size_t)(t >> 12) * NE + lane] * (ev / s);
    out[(size_t)t * NE + lane] = sc;

    // top-2 via packed key max-reduce
    const unsigned long long key =
        ((unsigned long long)__float_as_uint(sc) << 6) | (unsigned long long)(63 - lane);
    unsigned long long k1 = key;
#pragma unroll
    for (int m = 32; m; m >>= 1) {
        const unsigned long long o = __shfl_xor(k1, m, 64);
        if (o > k1) k1 = o;
    }
    const int   i1 = 63 - (int)(k1 & 63ull);
    const float v1 = __uint_as_float((unsigned)(k1 >> 6));

    unsigned long long k2 = (lane == i1) ? 0ull : key;
#pragma unroll
    for (int m = 32; m; m >>= 1) {
        const unsigned long long o = __shfl_xor(k2, m, 64);
        if (o > k2) k2 = o;
    }
    const int   i2 = 63 - (int)(k2 & 63ull);
    const float v2 = __uint_as_float((unsigned)(k2 >> 6));

    if (lane == 0) {
        const float e2v = __expf(v2 - v1);   // v1 >= v2
        float w1 = 1.f / (1.f + e2v);
        float w2 = e2v / (1.f + e2v);
        const float sw = w1 + w2;            // L1 renorm (kept for parity)
        w1 /= sw; w2 /= sw;
        const size_t wo = (size_t)2 * NTOK * NE;
        out[wo + (size_t)t * 2 + 0] = w1;
        out[wo + (size_t)t * 2 + 1] = w2;
        const size_t io = wo + (size_t)NTOK * 2;
        out[io + (size_t)t * 2 + 0] = (float)i1;
        out[io + (size_t)t * 2 + 1] = (float)i2;
    }
}

extern "C" void kernel_launch(void* const* d_in, const int* in_sizes, int n_in,
                              void* d_out, int out_size, void* d_ws, size_t ws_size,
                              hipStream_t stream) {
    const float* x    = (const float*)d_in[0];
    const float* mask = (const float*)d_in[1];
    const float* W    = (const float*)d_in[2];
    float* out = (float*)d_out;
    float* ws  = (float*)d_ws;

    // ws layout: 7 fp32 partials (28 MB) + wfh (512 KB) + wfl (512 KB)
    float* wspart = ws;
    uint4* wfh = (uint4*)(ws + (size_t)(KSPLIT - 1) * NTOK * NE);
    uint4* wfl = wfh + (size_t)NCHUNK * 4 * 64;
    float* part0 = out + (size_t)NTOK * NE;   // logits region

    prep_w<<<dim3(NCHUNK * 4 * 64 / 256), dim3(256), 0, stream>>>(W, wfh, wfl);
    gemm_logits_mfma<<<dim3(NTOK / TOKB, KSPLIT), dim3(128), 0, stream>>>(
        x, wfh, wfl, part0, wspart);
    router_kernel<<<dim3(NTOK / 4), dim3(256), 0, stream>>>(wspart, mask, out, KSPLIT);
}

// Round 19
// 74.248 us; speedup vs baseline: 1.1693x; 1.1693x over previous
//
#include <hip/hip_runtime.h>
#include <hip/hip_bf16.h>

#define NE     64
#define HDIM   4096
#define NTOK   16384
#define KSPLIT 4
#define KPER   (HDIM / KSPLIT)   // 1024
#define KC     32                // k per LDS tile
#define NT     (KPER / KC)       // 32 tiles per block
#define NCHUNK (HDIM / 32)       // 128 global k-chunks
#define TOKB   128               // tokens per block (4 waves x 32)
#define PT     130               // LDS token stride (floats): bank=(2k+t)%32, <=2-way

typedef __attribute__((ext_vector_type(8))) short bf16x8;   // 8 bf16 = 4 VGPR
typedef __attribute__((ext_vector_type(4))) float f32x4;    // MFMA acc

union FragU { uint4 u; bf16x8 v; };

// round-to-nearest-even f32 -> bf16 (bits), no NaN handling (inputs finite)
__device__ __forceinline__ unsigned rne_bf16(float f) {
    unsigned v = __float_as_uint(f);
    return (v + 0x7FFFu + ((v >> 16) & 1u)) >> 16;
}

// split 8 fp32 -> hi (truncate) + lo (rne of residual); numerics identical R4-R17
__device__ __forceinline__ void split8f(const float* s, FragU& hi, FragU& lo) {
#pragma unroll
    for (int w = 0; w < 4; ++w) {
        const unsigned u0 = __float_as_uint(s[2 * w]);
        const unsigned u1 = __float_as_uint(s[2 * w + 1]);
        const unsigned h0 = u0 & 0xFFFF0000u, h1 = u1 & 0xFFFF0000u;
        ((unsigned*)&hi.u)[w] = (h0 >> 16) | h1;
        const float l0 = __uint_as_float(u0) - __uint_as_float(h0);
        const float l1 = __uint_as_float(u1) - __uint_as_float(h1);
        ((unsigned*)&lo.u)[w] = rne_bf16(l0) | (rne_bf16(l1) << 16);
    }
}

// ---------------------------------------------------------------------------
// Pack W [64][4096] fp32 into MFMA B-fragment order, split hi/lo bf16.
// elem j of lane l at [(chunk*4+etile)*64+l] = W[etile*16+(l&15)][chunk*32+(l>>4)*8+j]
// ---------------------------------------------------------------------------
__global__ __launch_bounds__(256) void prep_w(
    const float* __restrict__ W, uint4* __restrict__ wfh, uint4* __restrict__ wfl) {
    const int idx = blockIdx.x * 256 + threadIdx.x;   // 32768 = 128*4*64
    const int l  = idx & 63;
    const int ce = idx >> 6;
    const int e  = ce & 3;
    const int c  = ce >> 2;
    const float* src = W + (size_t)(e * 16 + (l & 15)) * HDIM + c * 32 + (l >> 4) * 8;

    unsigned hw[4], lw[4];
#pragma unroll
    for (int w = 0; w < 4; ++w) {
        const float x0 = src[2 * w], x1 = src[2 * w + 1];
        const unsigned u0 = __float_as_uint(x0), u1 = __float_as_uint(x1);
        const unsigned h0 = u0 & 0xFFFF0000u, h1 = u1 & 0xFFFF0000u;
        hw[w] = (h0 >> 16) | h1;
        const float l0 = x0 - __uint_as_float(h0);
        const float l1 = x1 - __uint_as_float(h1);
        lw[w] = rne_bf16(l0) | (rne_bf16(l1) << 16);
    }
    wfh[idx] = make_uint4(hw[0], hw[1], hw[2], hw[3]);
    wfl[idx] = make_uint4(lw[0], lw[1], lw[2], lw[3]);
}

#define MFMA_STEP(AH0, AL0, AH1, AL1, WH, WL)                                          \
    _Pragma("unroll")                                                                   \
    for (int e = 0; e < 4; ++e) {                                                       \
        acc[0][e] = __builtin_amdgcn_mfma_f32_16x16x32_bf16(AH0.v, WH[e].v, acc[0][e], 0, 0, 0); \
        acc[0][e] = __builtin_amdgcn_mfma_f32_16x16x32_bf16(AL0.v, WH[e].v, acc[0][e], 0, 0, 0); \
        acc[0][e] = __builtin_amdgcn_mfma_f32_16x16x32_bf16(AH0.v, WL[e].v, acc[0][e], 0, 0, 0); \
        acc[1][e] = __builtin_amdgcn_mfma_f32_16x16x32_bf16(AH1.v, WH[e].v, acc[1][e], 0, 0, 0); \
        acc[1][e] = __builtin_amdgcn_mfma_f32_16x16x32_bf16(AL1.v, WH[e].v, acc[1][e], 0, 0, 0); \
        acc[1][e] = __builtin_amdgcn_mfma_f32_16x16x32_bf16(AH1.v, WL[e].v, acc[1][e], 0, 0, 0); \
    }

// ---------------------------------------------------------------------------
// GEMM via split-bf16 MFMA — EXACT R11 pipeline with ONE isolated change:
// KSPLIT 8 -> 4 (fp32 partials kept — R18 proved partial precision is a
// hard numerics constraint). Halves the partial round-trip (saves 32 MB)
// at the cost of 2 blocks/CU (8 waves) instead of 4 (16 waves).
// Per-value numerics identical to the 15x-passing R11 path.
// ---------------------------------------------------------------------------
__global__ __launch_bounds__(256) void gemm_logits_mfma(
    const float* __restrict__ x, const uint4* __restrict__ wfh,
    const uint4* __restrict__ wfl, float* __restrict__ part0,
    float* __restrict__ wspart) {
    __shared__ float xs[2][KC][PT];   // 33,280 B

    const int tid  = threadIdx.x;
    const int lane = tid & 63;
    const int wv   = tid >> 6;            // wave 0..3
    const int t0   = blockIdx.x * TOKB;
    const int bk   = blockIdx.y;          // 0..3 k-split
    const int r    = lane & 15;           // A token row in frag / B expert row
    const int u    = lane >> 4;           // 0..3 k-quad

    f32x4 acc[2][4];
#pragma unroll
    for (int f = 0; f < 2; ++f)
#pragma unroll
        for (int e = 0; e < 4; ++e) acc[f][e] = (f32x4){0.f, 0.f, 0.f, 0.f};

    // staging: 8 consecutive tids cover one row's 128B k-chunk (coalesced)
    const int srow = tid >> 3;            // 0..31 (+32p)
    const int skq  = tid & 7;
    const float* gsrc = x + (size_t)(t0 + srow) * HDIM + bk * KPER + skq * 4;

    const uint4* whb = wfh + (size_t)(bk * NT) * 256 + lane;
    const uint4* wlb = wfl + (size_t)(bk * NT) * 256 + lane;

    float4 ldE[4], ldO[4];
    FragU WhA[4], WlA[4], WhB[4], WlB[4];

#define LOADT(LD, T)                                                              \
    _Pragma("unroll")                                                             \
    for (int p = 0; p < 4; ++p)                                                   \
        LD[p] = *reinterpret_cast<const float4*>(gsrc + (size_t)(32 * p) * HDIM + (T) * KC);

#define WRITET(B, LD)                                                             \
    _Pragma("unroll")                                                             \
    for (int p = 0; p < 4; ++p) {                                                 \
        const int rr = srow + 32 * p;                                             \
        xs[B][skq * 4 + 0][rr] = LD[p].x;                                         \
        xs[B][skq * 4 + 1][rr] = LD[p].y;                                         \
        xs[B][skq * 4 + 2][rr] = LD[p].z;                                         \
        xs[B][skq * 4 + 3][rr] = LD[p].w;                                         \
    }

    // Prologue: W(0)->A; tiles 0,1,2 in flight; tile 0 written to buf0.
#pragma unroll
    for (int e = 0; e < 4; ++e) { WhA[e].u = whb[e * 64]; WlA[e].u = wlb[e * 64]; }
    LOADT(ldE, 0)
    LOADT(ldO, 1)
    WRITET(0, ldE)
    LOADT(ldE, 2)
    __syncthreads();

    const int crow = wv * 32 + r;

    for (int t2 = 0; t2 < NT; t2 += 2) {
        // ===== even tile t2: buf0, W set A; ldO holds tile t2+1 =====
        {
            const size_t c = (size_t)(t2 + 1) * 256;
#pragma unroll
            for (int e = 0; e < 4; ++e) { WhB[e].u = whb[c + e * 64]; WlB[e].u = wlb[c + e * 64]; }
            float a0[8], a1[8];
            const float* xb = &xs[0][0][0] + (u * 8) * PT + crow;
#pragma unroll
            for (int j = 0; j < 8; ++j) { a0[j] = xb[j * PT]; a1[j] = xb[j * PT + 16]; }
            FragU ah0, al0, ah1, al1;
            split8f(a0, ah0, al0);
            split8f(a1, ah1, al1);
            MFMA_STEP(ah0, al0, ah1, al1, WhA, WlA)
            WRITET(1, ldO)
            if (t2 + 3 < NT) { LOADT(ldO, t2 + 3) }
            __syncthreads();
        }
        // ===== odd tile t2+1: buf1, W set B; ldE holds tile t2+2 =====
        {
            const int tn = t2 + 2;
            if (tn < NT) {
                const size_t c = (size_t)tn * 256;
#pragma unroll
                for (int e = 0; e < 4; ++e) { WhA[e].u = whb[c + e * 64]; WlA[e].u = wlb[c + e * 64]; }
            }
            float a0[8], a1[8];
            const float* xb = &xs[1][0][0] + (u * 8) * PT + crow;
#pragma unroll
            for (int j = 0; j < 8; ++j) { a0[j] = xb[j * PT]; a1[j] = xb[j * PT + 16]; }
            FragU ah0, al0, ah1, al1;
            split8f(a0, ah0, al0);
            split8f(a1, ah1, al1);
            MFMA_STEP(ah0, al0, ah1, al1, WhB, WlB)
            if (tn < NT) {
                WRITET(0, ldE)
                if (t2 + 4 < NT) { LOADT(ldE, t2 + 4) }
                __syncthreads();
            }
        }
    }

    // D layout (m89-verified, identical to passing R4-R17): lane holds
    // D[token = wv*32 + f*16 + u*4 + reg][expert = e*16 + r]
    float* dst = (bk == 0 ? part0 : wspart + (size_t)(bk - 1) * NTOK * NE);
#pragma unroll
    for (int f = 0; f < 2; ++f)
#pragma unroll
        for (int e = 0; e < 4; ++e)
#pragma unroll
            for (int rr = 0; rr < 4; ++rr)
                dst[(size_t)(t0 + wv * 32 + f * 16 + u * 4 + rr) * NE + e * 16 + r] = acc[f][e][rr];
#undef LOADT
#undef WRITET
}

// ---------------------------------------------------------------------------
// Router: WAVE-PER-TOKEN, lane = expert (R11, proven). Coalesced 256B rows;
// softmax via shfl_xor butterflies; top-2 via packed 64-bit key max-reduce
// (tie -> lowest index, matching jax.lax.top_k; scores >= 0).
// Out layout: [scores 16384*64][logits 16384*64][weights 16384*2][indices 16384*2]
// ---------------------------------------------------------------------------
__global__ __launch_bounds__(256) void router_kernel(
    const float* __restrict__ wspart, const float* __restrict__ mask,
    float* __restrict__ out, int ksplit) {
    const int lane = threadIdx.x & 63;
    const int wv   = threadIdx.x >> 6;
    const int t    = blockIdx.x * 4 + wv;

    // logits: partial 0 lives in the out-logits region; add ws partials
    float* lo = out + (size_t)NTOK * NE + (size_t)t * NE;
    float l = lo[lane];
    for (int c = 1; c < ksplit; ++c)
        l += wspart[((size_t)(c - 1) * NTOK + t) * NE + lane];
    lo[lane] = l;

    // softmax over 64 lanes
    float mx = l;
#pragma unroll
    for (int m = 32; m; m >>= 1) mx = fmaxf(mx, __shfl_xor(mx, m, 64));
    const float ev = __expf(l - mx);
    float s = ev;
#pragma unroll
    for (int m = 32; m; m >>= 1) s += __shfl_xor(s, m, 64);
    const float sc = mask[(size_t)(t >> 12) * NE + lane] * (ev / s);
    out[(size_t)t * NE + lane] = sc;

    // top-2 via packed key max-reduce
    const unsigned long long key =
        ((unsigned long long)__float_as_uint(sc) << 6) | (unsigned long long)(63 - lane);
    unsigned long long k1 = key;
#pragma unroll
    for (int m = 32; m; m >>= 1) {
        const unsigned long long o = __shfl_xor(k1, m, 64);
        if (o > k1) k1 = o;
    }
    const int   i1 = 63 - (int)(k1 & 63ull);
    const float v1 = __uint_as_float((unsigned)(k1 >> 6));

    unsigned long long k2 = (lane == i1) ? 0ull : key;
#pragma unroll
    for (int m = 32; m; m >>= 1) {
        const unsigned long long o = __shfl_xor(k2, m, 64);
        if (o > k2) k2 = o;
    }
    const int   i2 = 63 - (int)(k2 & 63ull);
    const float v2 = __uint_as_float((unsigned)(k2 >> 6));

    if (lane == 0) {
        const float e2v = __expf(v2 - v1);   // v1 >= v2
        float w1 = 1.f / (1.f + e2v);
        float w2 = e2v / (1.f + e2v);
        const float sw = w1 + w2;            // L1 renorm (kept for parity)
        w1 /= sw; w2 /= sw;
        const size_t wo = (size_t)2 * NTOK * NE;
        out[wo + (size_t)t * 2 + 0] = w1;
        out[wo + (size_t)t * 2 + 1] = w2;
        const size_t io = wo + (size_t)NTOK * 2;
        out[io + (size_t)t * 2 + 0] = (float)i1;
        out[io + (size_t)t * 2 + 1] = (float)i2;
    }
}

extern "C" void kernel_launch(void* const* d_in, const int* in_sizes, int n_in,
                              void* d_out, int out_size, void* d_ws, size_t ws_size,
                              hipStream_t stream) {
    const float* x    = (const float*)d_in[0];
    const float* mask = (const float*)d_in[1];
    const float* W    = (const float*)d_in[2];
    float* out = (float*)d_out;
    float* ws  = (float*)d_ws;

    // ws layout: 3 fp32 partials (12 MB) + wfh (512 KB) + wfl (512 KB)
    float* wspart = ws;
    uint4* wfh = (uint4*)(ws + (size_t)(KSPLIT - 1) * NTOK * NE);
    uint4* wfl = wfh + (size_t)NCHUNK * 4 * 64;
    float* part0 = out + (size_t)NTOK * NE;   // logits region

    prep_w<<<dim3(NCHUNK * 4 * 64 / 256), dim3(256), 0, stream>>>(W, wfh, wfl);
    gemm_logits_mfma<<<dim3(NTOK / TOKB, KSPLIT), dim3(256), 0, stream>>>(
        x, wfh, wfl, part0, wspart);
    router_kernel<<<dim3(NTOK / 4), dim3(256), 0, stream>>>(wspart, mask, out, KSPLIT);
}